// Round 17
// baseline (847.955 us; speedup 1.0000x reference)
//
#include <hip/hip_runtime.h>
#include <math.h>

typedef unsigned short u16;
typedef unsigned int u32;
typedef __attribute__((ext_vector_type(8))) short bf16x8;
typedef __attribute__((ext_vector_type(4))) float f32x4;

#define HWW 6144

__device__ __forceinline__ float sigmoidf_(float x) { return 1.f / (1.f + expf(-x)); }
__device__ __forceinline__ float lrelu_(float x) { return x >= 0.f ? x : 0.01f * x; }
__device__ __forceinline__ u16 f2bf(float f) {
    u32 u = __float_as_uint(f);
    u += 0x7fffu + ((u >> 16) & 1u);
    return (u16)(u >> 16);
}
__device__ __forceinline__ float bf2f(u16 h) { return __uint_as_float(((u32)h) << 16); }
__device__ __forceinline__ u32 pk2(float a, float b) { return (u32)f2bf(a) | ((u32)f2bf(b) << 16); }

// async global->LDS DMA: per-lane global src, wave-uniform LDS base + lane*16
__device__ __forceinline__ void gload_lds16(const u16* g, u16* l) {
    __builtin_amdgcn_global_load_lds((const __attribute__((address_space(1))) void*)g,
                                     (__attribute__((address_space(3))) void*)l, 16, 0, 0);
}

template<int N> __device__ __forceinline__ void waitcnt_vm() {
    if constexpr (N == 0) asm volatile("s_waitcnt vmcnt(0)" ::: "memory");
    else if constexpr (N == 2) asm volatile("s_waitcnt vmcnt(2)" ::: "memory");
    else if constexpr (N == 3) asm volatile("s_waitcnt vmcnt(3)" ::: "memory");
    else if constexpr (N == 4) asm volatile("s_waitcnt vmcnt(4)" ::: "memory");
    else if constexpr (N == 5) asm volatile("s_waitcnt vmcnt(5)" ::: "memory");
    else if constexpr (N == 6) asm volatile("s_waitcnt vmcnt(6)" ::: "memory");
    else asm volatile("s_waitcnt vmcnt(0)" ::: "memory");
}
__device__ __forceinline__ void barrier_raw() {
    asm volatile("" ::: "memory");
    __builtin_amdgcn_s_barrier();
    asm volatile("" ::: "memory");
}

// ======== fused weight transpose (16 jobs in one launch) ========
struct WJob { const float* src; unsigned long dstOff; int OC, rowOff, IC, ICP, NT; unsigned long cum; };
struct WJobs { WJob j[16]; long total; };

__global__ __launch_bounds__(256) void k_wt_all(WJobs J, u16* __restrict__ base)
{
    long i = (long)blockIdx.x * 256 + threadIdx.x;
    if (i >= J.total) return;
    int jb = 0;
    #pragma unroll
    for (int k = 1; k < 16; ++k) if (i >= (long)J.j[k].cum) jb = k;
    WJob w = J.j[jb];
    long local = i - (long)w.cum;
    int c = (int)(local % w.ICP);
    int t = (int)((local / w.ICP) % w.NT);
    int o = (int)(local / ((long)w.ICP * w.NT));
    float val = (c < w.IC) ? w.src[((long)o * w.IC + c) * w.NT + t] : 0.f;
    base[w.dstOff + ((long)(w.rowOff + o) * w.NT + t) * w.ICP + c] = f2bf(val);
}

__global__ __launch_bounds__(256) void k_wt_dq(const float* __restrict__ w, u16* __restrict__ dst)
{
    int i = blockIdx.x * 256 + threadIdx.x;
    if (i >= 32768) return;
    int c = i & 63; int t = (i >> 6) & 3; int o = (i >> 8) & 31; int q = i >> 13;
    int ry = q >> 1, rx = q & 1, ta = t >> 1, tb = t & 1;
    int ky = ry + 2 * ta, kx = rx + 2 * tb;
    float val = w[(((long)o * 64 + c) * 4 + ky) * 4 + kx];
    dst[(long)q * 8192 + o * 256 + t * 64 + c] = f2bf(val);
}

__global__ __launch_bounds__(256) void k_wt5(const float* __restrict__ w, float* __restrict__ wt)
{
    int i = blockIdx.x * 256 + threadIdx.x;
    if (i >= 288) return;
    int t = i % 9, c = i / 9;
    wt[t * 32 + c] = w[c * 9 + t];
}

__global__ void k_catb(const float* __restrict__ a, const float* __restrict__ b, float* __restrict__ d)
{
    int i = threadIdx.x;
    if (i < 128) d[i] = a[i];
    else if (i < 256) d[i] = b[i - 128];
}

// ======== elementwise / prep kernels ========
__global__ __launch_bounds__(256) void k_prep_f1(const float* __restrict__ fmap1, u16* __restrict__ f1bf)
{
    int gid = blockIdx.x * 256 + threadIdx.x;
    if (gid >= 24576) return;
    int idx = gid >> 1, half = gid & 1;
    int b = idx / HWW, p = idx % HWW;
    const float* fb = fmap1 + (long)b * 32 * HWW + p + (long)(half * 16) * HWW;
    u32 pk[8];
    #pragma unroll
    for (int c2 = 0; c2 < 8; ++c2)
        pk[c2] = pk2(fb[(long)(2 * c2) * HWW], fb[(long)(2 * c2 + 1) * HWW]);
    u16* op = f1bf + ((long)idx << 5) + half * 16;
    ((uint4*)op)[0] = make_uint4(pk[0], pk[1], pk[2], pk[3]);
    ((uint4*)op)[1] = make_uint4(pk[4], pk[5], pk[6], pk[7]);
}

__global__ __launch_bounds__(256) void k_warp(const float* __restrict__ fmap2, const float* __restrict__ flow,
                                              u16* __restrict__ f2wbf, float* __restrict__ cs)
{
    int gid = blockIdx.x * 256 + threadIdx.x;
    if (gid >= 24576) return;
    int idx = gid >> 1, half = gid & 1;
    int b = idx / HWW, p = idx % HWW, y = p / 96, x = p % 96;
    float u = flow[(b * 2 + 0) * HWW + p], v = flow[(b * 2 + 1) * HWW + p];
    float fx = (float)x + u, fy = (float)y + v;
    float fx0 = floorf(fx), fy0 = floorf(fy);
    float wx = fx - fx0, wy = fy - fy0;
    int x0 = (int)fx0, y0i = (int)fy0, x1 = x0 + 1, y1 = y0i + 1;
    bool vx0 = x0 >= 0 && x0 < 96, vx1 = x1 >= 0 && x1 < 96;
    bool vy0 = y0i >= 0 && y0i < 64, vy1 = y1 >= 0 && y1 < 64;
    float m00 = (vy0 && vx0) ? (1.f - wy) * (1.f - wx) : 0.f;
    float m01 = (vy0 && vx1) ? (1.f - wy) * wx : 0.f;
    float m10 = (vy1 && vx0) ? wy * (1.f - wx) : 0.f;
    float m11 = (vy1 && vx1) ? wy * wx : 0.f;
    int cx0 = min(max(x0, 0), 95), cx1 = min(max(x1, 0), 95);
    int cy0 = min(max(y0i, 0), 63), cy1 = min(max(y1, 0), 63);
    int i00 = cy0 * 96 + cx0, i01 = cy0 * 96 + cx1, i10 = cy1 * 96 + cx0, i11 = cy1 * 96 + cx1;
    const float* fb = fmap2 + (long)b * 32 * HWW + (long)(half * 16) * HWW;
    float s = 0.f; u32 pk[8];
    #pragma unroll
    for (int c2 = 0; c2 < 8; ++c2) {
        const float* fa = fb + (long)(2 * c2) * HWW;
        const float* fc = fb + (long)(2 * c2 + 1) * HWW;
        float g0 = m00 * fa[i00] + m01 * fa[i01] + m10 * fa[i10] + m11 * fa[i11];
        float g1 = m00 * fc[i00] + m01 * fc[i01] + m10 * fc[i10] + m11 * fc[i11];
        s += g0 + g1;
        pk[c2] = pk2(g0, g1);
    }
    u16* op = f2wbf + ((long)idx << 5) + half * 16;
    ((uint4*)op)[0] = make_uint4(pk[0], pk[1], pk[2], pk[3]);
    ((uint4*)op)[1] = make_uint4(pk[4], pk[5], pk[6], pk[7]);
    float stot = s + __shfl_xor(s, 1);
    if (half == 0) cs[idx] = stot;
}

// ======== MFMA implicit GEMM: DMA staging, 3-buffer LDS, 1-barrier counted-vmcnt phase ========
// BM: 256/128/64. BN: 128/96/64/32. MODE 0: conv NHWC; 1: conv1 mvol; 2: deconv quad (blockIdx.z)
// OUTF32: 0 bf16 out (+outb2), 1 f32 out, 2 GRU zr fuse, 3 GRU q fuse (mid), 4 GRU q fuse (final)
template<int BM, int BN, int MODE, int KH, int KW, int PH, int PW, int STRIDE, int ACT, int OUTF32,
         int IH, int IW, int OH, int OW, int ICP, int NKT>
__global__ __launch_bounds__(256) void k_gemm(
    const u16* __restrict__ A0, const u16* __restrict__ A1,
    const float* __restrict__ csm, const u16* __restrict__ Wb,
    const float* __restrict__ bias, const u16* __restrict__ zpg,
    u16* __restrict__ outb, u16* __restrict__ outb2, float* __restrict__ outf,
    int OC, int ldc, int coff, int nOff)
{
    constexpr int WAVES_N = (BN >= 128) ? 2 : 1;
    constexpr int WAVES_M = 4 / WAVES_N;
    constexpr int WTM = BM / WAVES_M;
    constexpr int WTN = BN / WAVES_N;
    constexpr int MF = WTM / 16;
    constexpr int NF = WTN / 16;
    __shared__ u16 As[3][BM * 32];
    __shared__ u16 Bs[3][BN * 32];
    __shared__ u16 dmy[512];
    int tid = threadIdx.x, lane = tid & 63, wid = tid >> 6;
    constexpr int AIW = BM / 64;            // A DMA instrs per wave
    constexpr int BG  = BN / 16;            // B 16-row groups
    constexpr int BJW = (BG + 3) / 4;       // B DMA slots per wave (uniform; invalid -> dummy)
    constexpr int LPS = AIW + BJW;          // DMA instrs per lane per stage (uniform)
    int ryz = 0, rxz = 0;
    if (MODE == 2) { ryz = blockIdx.z >> 1; rxz = blockIdx.z & 1; }
    const u16* WbZ = Wb + (MODE == 2 ? (long)blockIdx.z * 32 * 256 : 0);
    int n0 = blockIdx.y * BN;
    int chunk = lane & 3, sub = lane >> 2;

    // ---- per-lane A staging state (AIW rows per lane, decoded once) ----
    const u16* aB0[AIW]; const u16* aB1[AIW]; u32 am[AIW];
    #pragma unroll
    for (int j = 0; j < AIW; ++j) {
        int row = wid * (BM / 4) + j * 16 + sub;
        int gm = blockIdx.x * BM + row;
        constexpr int OHW = (MODE == 1) ? 6144 : ((MODE == 2) ? 1536 : OH * OW);
        constexpr int OWW = (MODE == 1) ? 96 : ((MODE == 2) ? 48 : OW);
        int nI = gm / OHW, rem = gm - nI * OHW;
        int y0 = rem / OWW, x0 = rem - y0 * OWW;
        aB1[j] = A0; am[j] = 0;
        if (MODE == 0) {
            aB0[j] = A0 + ((long)nI * IH * IW + (long)y0 * STRIDE * IW + (long)x0 * STRIDE) * ICP + chunk * 8;
            u32 m = 0;
            #pragma unroll
            for (int t = 0; t < KH * KW; ++t) {
                int dy = t / KW - PH, dx = t % KW - PW;
                int iy = y0 * STRIDE + dy, ix = x0 * STRIDE + dx;
                m |= ((iy >= 0 && iy < IH && ix >= 0 && ix < IW) ? 1u : 0u) << t;
            }
            am[j] = m;
        } else if (MODE == 1) {
            int n = nOff + nI, bI = n / 49, kd = n - bI * 49;
            int di = kd / 7 - 3, dj = kd % 7 - 3;
            long bH = (long)bI * 6144;
            aB0[j] = A0 + ((bH + rem) << 5) + chunk * 8;
            aB1[j] = A1 + ((bH + (y0 + dj) * 96 + (x0 + di)) << 5) + chunk * 8;
            u32 m = 0;
            #pragma unroll
            for (int t = 0; t < 9; ++t) {
                int dy = t / 3 - 1, dx = t % 3 - 1;
                int yy = y0 + dy, xx = x0 + dx, ys = yy + dj, xs = xx + di;
                bool v = yy >= 0 && yy < 64 && xx >= 0 && xx < 96 && ys >= 0 && ys < 64 && xs >= 0 && xs < 96;
                if (v) v = (csm[bI * 6144 + ys * 96 + xs] != 0.f);
                m |= (v ? 1u : 0u) << t;
            }
            am[j] = m;
        } else {
            int iy0 = y0 + ryz - 1, ix0 = x0 + rxz - 1;
            aB0[j] = A0 + ((long)nI * 1536 + (long)iy0 * 48 + ix0) * 64 + chunk * 8;
            u32 m = 0;
            #pragma unroll
            for (int t = 0; t < 4; ++t) {
                int ta = t >> 1, tb = t & 1;
                int iy = iy0 + ta, ix = ix0 + tb;
                m |= ((iy >= 0 && iy < 32 && ix >= 0 && ix < 48) ? 1u : 0u) << t;
            }
            am[j] = m;
        }
    }
    // ---- per-lane B staging state: wave w stages 16-row groups g = w + 4j ----
    const u16* bB[BJW];
    #pragma unroll
    for (int j = 0; j < BJW; ++j) {
        int g = wid + 4 * j;
        int gc = (g < BG) ? g : 0;
        bB[j] = WbZ + (long)(n0 + gc * 16 + sub) * (NKT * 32) + chunk * 8;
    }

    auto stage = [&](int kt, int bn) {
        #pragma unroll
        for (int j = 0; j < AIW; ++j) {
            const u16* g;
            if (MODE == 0) {
                constexpr int KTC = ICP / 32;
                int t = kt / KTC, c0 = (kt - t * KTC) << 5;
                int dy = t / KW - PH, dx = t % KW - PW;
                bool v = (am[j] >> t) & 1u;
                g = v ? aB0[j] + (long)(dy * IW + dx) * ICP + c0 : zpg;
            } else if (MODE == 1) {
                int t = kt >> 1, half = kt & 1;
                int dy = t / 3 - 1, dx = t % 3 - 1;
                bool v = (am[j] >> t) & 1u;
                const u16* b = half ? aB1[j] : aB0[j];
                g = v ? b + ((dy * 96 + dx) << 5) : zpg;
            } else {
                int t = kt >> 1, c0 = (kt & 1) << 5;
                int ta = t >> 1, tb = t & 1;
                bool v = (am[j] >> t) & 1u;
                g = v ? aB0[j] + (ta * 48 + tb) * 64 + c0 : zpg;
            }
            gload_lds16(g, &As[bn][(wid * (BM / 4) + j * 16) * 32]);
        }
        #pragma unroll
        for (int j = 0; j < BJW; ++j) {
            int g = wid + 4 * j;
            if (g < BG) gload_lds16(bB[j] + kt * 32, &Bs[bn][g * 512]);
            else gload_lds16(zpg, dmy);
        }
    };

    int wm = (WAVES_N == 2) ? (wid >> 1) : wid;
    int wn = (WAVES_N == 2) ? (wid & 1) : 0;
    int fr = lane & 15, fg = lane >> 4;
    f32x4 acc[MF][NF];
    #pragma unroll
    for (int i = 0; i < MF; ++i)
        #pragma unroll
        for (int j = 0; j < NF; ++j)
            acc[i][j] = (f32x4){0.f, 0.f, 0.f, 0.f};

    // prologue: stage kt=0,1 into buffers 0,1; wait for kt=0 only (kt=1 stays in flight)
    stage(0, 0);
    if (NKT > 1) stage(1, 1);
    if (NKT > 1) waitcnt_vm<LPS>(); else waitcnt_vm<0>();
    barrier_raw();

    // one-barrier phase: stage(kt+2) | MFMA(kt) | waitcnt(kt+1 landed) | barrier
    #pragma unroll
    for (int kt = 0; kt < NKT; ++kt) {
        int cur = kt % 3;
        if (kt + 2 < NKT) stage(kt + 2, (kt + 2) % 3);
        bf16x8 af[MF], bv[NF];
        #pragma unroll
        for (int i = 0; i < MF; ++i)
            af[i] = *(const bf16x8*)&As[cur][(wm * WTM + i * 16 + fr) * 32 + fg * 8];
        #pragma unroll
        for (int j = 0; j < NF; ++j)
            bv[j] = *(const bf16x8*)&Bs[cur][(wn * WTN + j * 16 + fr) * 32 + fg * 8];
        #pragma unroll
        for (int i = 0; i < MF; ++i)
            #pragma unroll
            for (int j = 0; j < NF; ++j)
                acc[i][j] = __builtin_amdgcn_mfma_f32_16x16x32_bf16(af[i], bv[j], acc[i][j], 0, 0, 0);
        if (kt + 1 < NKT) {
            if (kt + 2 < NKT) waitcnt_vm<LPS>();   // kt+1's DMAs done; kt+2's stay in flight
            else waitcnt_vm<0>();                  // tail: drain kt+1
            barrier_raw();                         // kt+1 data visible to all waves
        }
    }

    // epilogue
    #pragma unroll
    for (int i = 0; i < MF; ++i) {
        #pragma unroll
        for (int j = 0; j < NF; ++j) {
            int nn = n0 + wn * WTN + j * 16 + fr;
            if (nn >= OC) continue;
            #pragma unroll
            for (int rr = 0; rr < 4; ++rr) {
                int mloc = wm * WTM + i * 16 + fg * 4 + rr;
                long gm = (long)blockIdx.x * BM + mloc;
                float v = acc[i][j][rr] + bias[nn];
                if (ACT == 1) v = fmaxf(v, 0.f);
                else if (ACT == 2) v = lrelu_(v);
                if (OUTF32 == 1) {
                    outf[gm * ldc + coff + nn] = v;
                } else if (OUTF32 == 2) {
                    float s = sigmoidf_(v);
                    if (nn < 128) outf[gm * 128 + nn] = s;
                    else outb[gm * 224 + (nn - 128)] = f2bf(s * csm[gm * 128 + (nn - 128)]);
                } else if (OUTF32 == 3 || OUTF32 == 4) {
                    float zv = ((const float*)A1)[gm * 128 + nn];
                    float hnew = (1.f - zv) * csm[gm * 128 + nn] + zv * tanhf(v);
                    if (OUTF32 == 3) {
                        outf[gm * 128 + nn] = hnew;
                        outb[gm * 224 + nn] = f2bf(hnew);
                    } else {
                        int bb = (int)(gm / 6144), pp = (int)(gm - (long)bb * 6144);
                        outf[((long)(bb * 128 + nn)) * 6144 + pp] = hnew;
                        outb[gm * 128 + nn] = f2bf(hnew);
                    }
                } else if (MODE == 2) {
                    int nI = (int)(gm / 1536); int rq = (int)(gm - (long)nI * 1536);
                    int Y = rq / 48, X = rq - (rq / 48) * 48;
                    long di = (((long)nI * 64 + 2 * Y + ryz) * 96 + (2 * X + rxz)) * 32 + nn;
                    outb[di] = f2bf(v);
                } else {
                    long di = gm * ldc + coff + nn;
                    u16 hv = f2bf(v);
                    outb[di] = hv;
                    if (outb2) outb2[di] = hv;
                }
            }
        }
    }
}

// ======== conv5 (32->1, 3x3) scalar over NHWC bf16 -> cvolT [b][p][64] bf16 ========
__global__ __launch_bounds__(256) void k_conv5n(const u16* __restrict__ x5, const float* __restrict__ w5t,
                                                const float* __restrict__ b5, u16* __restrict__ cvolT,
                                                int N, int n0)
{
    int idx = blockIdx.x * 256 + threadIdx.x;
    if (idx >= N * HWW) return;
    int nl = idx / HWW, p = idx % HWW, y = p / 96, x = p % 96;
    float acc = b5[0];
    #pragma unroll
    for (int t = 0; t < 9; ++t) {
        int iy = y + t / 3 - 1, ix = x + t % 3 - 1;
        if (iy < 0 || iy >= 64 || ix < 0 || ix >= 96) continue;
        const u16* sp = x5 + (((long)nl * HWW + iy * 96 + ix) << 5);
        const float* wt_ = w5t + t * 32;
        #pragma unroll
        for (int c8 = 0; c8 < 4; ++c8) {
            uint4 v = *(const uint4*)(sp + c8 * 8);
            acc = fmaf(bf2f((u16)(v.x & 0xffffu)), wt_[c8 * 8 + 0], acc);
            acc = fmaf(bf2f((u16)(v.x >> 16)),     wt_[c8 * 8 + 1], acc);
            acc = fmaf(bf2f((u16)(v.y & 0xffffu)), wt_[c8 * 8 + 2], acc);
            acc = fmaf(bf2f((u16)(v.y >> 16)),     wt_[c8 * 8 + 3], acc);
            acc = fmaf(bf2f((u16)(v.z & 0xffffu)), wt_[c8 * 8 + 4], acc);
            acc = fmaf(bf2f((u16)(v.z >> 16)),     wt_[c8 * 8 + 5], acc);
            acc = fmaf(bf2f((u16)(v.w & 0xffffu)), wt_[c8 * 8 + 6], acc);
            acc = fmaf(bf2f((u16)(v.w >> 16)),     wt_[c8 * 8 + 7], acc);
        }
    }
    int n = n0 + nl;
    int b = n / 49, k = n - b * 49;
    cvolT[((long)b * HWW + p) * 64 + k] = f2bf(acc);
}

// ======== mein ch 49..95 (fmap1, flow, zero-pad); 6-way channel split ========
__global__ __launch_bounds__(256) void k_me_tail(const float* __restrict__ fmap1, const float* __restrict__ flow,
                                                 u16* __restrict__ mein)
{
    int gid = blockIdx.x * 256 + threadIdx.x;
    if (gid >= 73728) return;
    int j = gid / 12288, idx = gid - j * 12288;
    int b = idx / HWW, p = idx % HWW;
    int c0 = 49 + j * 8;
    u16* mp = mein + (long)idx * 96;
    #pragma unroll
    for (int q = 0; q < 8; ++q) {
        int c = c0 + q;
        if (c >= 96) break;
        float v;
        if (c < 81) v = fmap1[((long)(b * 32 + (c - 49))) * HWW + p];
        else if (c == 81) v = flow[(b * 2 + 0) * HWW + p];
        else if (c == 82) v = flow[(b * 2 + 1) * HWW + p];
        else v = 0.f;
        mp[c] = f2bf(v);
    }
}

// ======== set hx head from h (NCHW f32) + hst + flow tails; 4-way channel split ========
__global__ __launch_bounds__(256) void k_set_head(const float* __restrict__ h, const float* __restrict__ flow,
                                                  float* __restrict__ hst, u16* __restrict__ hx,
                                                  u16* __restrict__ hx2)
{
    int gid = blockIdx.x * 256 + threadIdx.x;
    if (gid >= 49152) return;
    int cq = gid / 12288, idx = gid - cq * 12288;
    int b = idx / HWW, p = idx % HWW;
    int c0 = cq * 32;
    const float* hp = h + (long)b * 128 * HWW + p;
    float* hs = hst + (long)idx * 128;
    u16* hxp = hx + (long)idx * 224;
    #pragma unroll
    for (int c = c0; c < c0 + 32; c += 8) {
        float v[8];
        #pragma unroll
        for (int q = 0; q < 8; ++q) v[q] = hp[(long)(c + q) * HWW];
        *(float4*)&hs[c] = make_float4(v[0], v[1], v[2], v[3]);
        *(float4*)&hs[c + 4] = make_float4(v[4], v[5], v[6], v[7]);
        uint4 pk = make_uint4(pk2(v[0], v[1]), pk2(v[2], v[3]), pk2(v[4], v[5]), pk2(v[6], v[7]));
        *(uint4*)&hxp[c] = pk;
    }
    if (cq == 0) {
        u16 uu = f2bf(flow[(b * 2 + 0) * HWW + p]);
        u16 vv = f2bf(flow[(b * 2 + 1) * HWW + p]);
        long o = (long)idx * 224;
        hx[o + 222] = uu; hx[o + 223] = vv;
        hx2[o + 222] = uu; hx2[o + 223] = vv;
    }
}

// ======== softmax + expectation + flow add ========
__global__ __launch_bounds__(256) void k_soft(const float* __restrict__ s2, const float* __restrict__ flow,
                                              float* __restrict__ outFlow)
{
    int idx = blockIdx.x * 256 + threadIdx.x;
    if (idx >= 12288) return;
    int b = idx / HWW, p = idx % HWW;
    const float* sp = s2 + (long)idx * 64;
    float lg[49];
    #pragma unroll
    for (int k = 0; k < 48; k += 4) {
        float4 v = *(const float4*)&sp[k];
        lg[k] = v.x; lg[k + 1] = v.y; lg[k + 2] = v.z; lg[k + 3] = v.w;
    }
    lg[48] = sp[48];
    float m = -1e30f;
    #pragma unroll
    for (int k = 0; k < 49; ++k) m = fmaxf(m, lg[k]);
    float s = 0.f, a0 = 0.f, a1 = 0.f;
    #pragma unroll
    for (int k = 0; k < 49; ++k) {
        float e = expf(lg[k] - m);
        s += e;
        a0 += e * (float)(k / 7 - 3);
        a1 += e * (float)(k % 7 - 3);
    }
    float inv = 1.f / s;
    outFlow[(long)(b * 2 + 0) * HWW + p] = flow[(long)(b * 2 + 0) * HWW + p] + a0 * inv;
    outFlow[(long)(b * 2 + 1) * HWW + p] = flow[(long)(b * 2 + 1) * HWW + p] + a1 * inv;
}

extern "C" void kernel_launch(void* const* d_in, const int* in_sizes, int n_in,
                              void* d_out, int out_size, void* d_ws, size_t ws_size,
                              hipStream_t stream)
{
    const float* fmap1 = (const float*)d_in[0];
    const float* fmap2 = (const float*)d_in[1];
    const float* h     = (const float*)d_in[2];
    const float* flow  = (const float*)d_in[3];
    int pb = (in_sizes[4] == 1) ? 5 : 4;
    const float* mn_w1 = (const float*)d_in[pb + 0];
    const float* mn_b1 = (const float*)d_in[pb + 1];
    const float* mn_w2 = (const float*)d_in[pb + 2];
    const float* mn_b2 = (const float*)d_in[pb + 3];
    const float* mn_w3 = (const float*)d_in[pb + 4];
    const float* mn_b3 = (const float*)d_in[pb + 5];
    const float* mn_w4 = (const float*)d_in[pb + 6];
    const float* mn_b4 = (const float*)d_in[pb + 7];
    const float* mn_wd = (const float*)d_in[pb + 8];
    const float* mn_bd = (const float*)d_in[pb + 9];
    const float* mn_w5 = (const float*)d_in[pb + 10];
    const float* mn_b5 = (const float*)d_in[pb + 11];
    const float* dap_w = (const float*)d_in[pb + 12];
    const float* dap_b = (const float*)d_in[pb + 13];
    const float* me_w1 = (const float*)d_in[pb + 14];
    const float* me_b1 = (const float*)d_in[pb + 15];
    const float* me_w2 = (const float*)d_in[pb + 16];
    const float* me_b2 = (const float*)d_in[pb + 17];
    const float* me_w3 = (const float*)d_in[pb + 18];
    const float* me_b3 = (const float*)d_in[pb + 19];
    const float* gz1_w = (const float*)d_in[pb + 20];
    const float* gz1_b = (const float*)d_in[pb + 21];
    const float* gr1_w = (const float*)d_in[pb + 22];
    const float* gr1_b = (const float*)d_in[pb + 23];
    const float* gq1_w = (const float*)d_in[pb + 24];
    const float* gq1_b = (const float*)d_in[pb + 25];
    const float* gz2_w = (const float*)d_in[pb + 26];
    const float* gz2_b = (const float*)d_in[pb + 27];
    const float* gr2_w = (const float*)d_in[pb + 28];
    const float* gr2_b = (const float*)d_in[pb + 29];
    const float* gq2_w = (const float*)d_in[pb + 30];
    const float* gq2_b = (const float*)d_in[pb + 31];
    const float* fh_w1 = (const float*)d_in[pb + 32];
    const float* fh_b1 = (const float*)d_in[pb + 33];
    const float* fh_w2 = (const float*)d_in[pb + 34];
    const float* fh_b2 = (const float*)d_in[pb + 35];

    char* wsB = (char*)d_ws;
    size_t off = 0;
    auto alc = [&](size_t bytes) { size_t o = off; off = (off + bytes + 255) & ~(size_t)255; return o; };

    // ---- weight arena (memset to 0 first; includes zero-page) ----
    size_t o_zpg  = alc(256);
    size_t o_wc1  = alc(128 * 576 * 2);
    size_t o_wc2  = alc(128 * 864 * 2);
    size_t o_wc3  = alc((size_t)128 * 1152 * 2);
    size_t o_wc4  = alc((size_t)64 * 1152 * 2);
    size_t o_wdq  = alc(32768 * 2);
    size_t o_wme1 = alc(128 * 864 * 2);
    size_t o_wme2 = alc((size_t)128 * 1152 * 2);
    size_t o_wme3 = alc((size_t)128 * 1152 * 2);
    size_t o_wzr1 = alc((size_t)256 * 1120 * 2);
    size_t o_wq1  = alc((size_t)128 * 1120 * 2);
    size_t o_wzr2 = alc((size_t)256 * 1120 * 2);
    size_t o_wq2  = alc((size_t)128 * 1120 * 2);
    size_t o_wfh1 = alc(256 * 128 * 2);
    size_t o_wfh2 = alc(64 * 256 * 2);
    size_t o_wdapb= alc(64 * 64 * 2);
    size_t o_w5t  = alc(288 * 4);
    size_t o_bzr1 = alc(256 * 4);
    size_t o_bzr2 = alc(256 * 4);
    size_t wArenaBytes = off;

    // ---- persistent activations ----
    size_t o_f1bf = alc((size_t)12288 * 32 * 2);
    size_t o_f2wb = alc((size_t)12288 * 32 * 2);
    size_t o_cs   = alc(12288 * 4);
    size_t o_cvolT= alc((size_t)12288 * 64 * 2);

    // ---- shared region: phase-A x-scratch overlaid with phase-B buffers ----
    const int CH = 49;
    size_t sharedBase = off;
    size_t offA = sharedBase;
    auto alcA = [&](size_t bytes) { size_t o = offA; offA = (offA + bytes + 255) & ~(size_t)255; return o; };
    size_t o_x1 = alcA((size_t)CH * 6144 * 96 * 2);
    size_t o_x2 = alcA((size_t)98 * 1536 * 128 * 2);
    size_t o_x3 = alcA((size_t)98 * 1536 * 128 * 2);
    size_t o_x4 = alcA((size_t)98 * 1536 * 64 * 2);
    size_t o_x5 = alcA((size_t)98 * 6144 * 32 * 2);
    size_t offB2 = sharedBase;
    auto alcB = [&](size_t bytes) { size_t o = offB2; offB2 = (offB2 + bytes + 255) & ~(size_t)255; return o; };
    size_t o_mein = alcB((size_t)12288 * 96 * 2);
    size_t o_m1   = alcB((size_t)12288 * 128 * 2);
    size_t o_m2   = alcB((size_t)12288 * 128 * 2);
    size_t o_hx   = alcB((size_t)12288 * 224 * 2);
    size_t o_hx2  = alcB((size_t)12288 * 224 * 2);
    size_t o_h2bf = alcB((size_t)12288 * 128 * 2);
    size_t o_s1b  = alcB((size_t)12288 * 256 * 2);
    size_t o_hst  = alcB((size_t)12288 * 128 * 4);
    size_t o_h1f  = alcB((size_t)12288 * 128 * 4);
    size_t o_zf   = alcB((size_t)12288 * 128 * 4);
    size_t o_s2   = alcB((size_t)12288 * 64 * 4);

    u16* wbase = (u16*)wsB;
    u16* zpg  = (u16*)(wsB + o_zpg);
    u16* wdq  = (u16*)(wsB + o_wdq);
    float* w5t = (float*)(wsB + o_w5t);
    float* bzr1 = (float*)(wsB + o_bzr1);
    float* bzr2 = (float*)(wsB + o_bzr2);
    u16* wc1  = (u16*)(wsB + o_wc1);   u16* wc2  = (u16*)(wsB + o_wc2);
    u16* wc3  = (u16*)(wsB + o_wc3);   u16* wc4  = (u16*)(wsB + o_wc4);
    u16* wme1 = (u16*)(wsB + o_wme1);  u16* wme2 = (u16*)(wsB + o_wme2);
    u16* wme3 = (u16*)(wsB + o_wme3);
    u16* wzr1 = (u16*)(wsB + o_wzr1);  u16* wq1  = (u16*)(wsB + o_wq1);
    u16* wzr2 = (u16*)(wsB + o_wzr2);  u16* wq2  = (u16*)(wsB + o_wq2);
    u16* wfh1 = (u16*)(wsB + o_wfh1);  u16* wfh2 = (u16*)(wsB + o_wfh2);
    u16* wdapb= (u16*)(wsB + o_wdapb);

    u16* f1bf = (u16*)(wsB + o_f1bf);  u16* f2wb = (u16*)(wsB + o_f2wb);
    float* cs = (float*)(wsB + o_cs);
    u16* cvolT = (u16*)(wsB + o_cvolT);
    u16* x1 = (u16*)(wsB + o_x1); u16* x2 = (u16*)(wsB + o_x2); u16* x3 = (u16*)(wsB + o_x3);
    u16* x4 = (u16*)(wsB + o_x4); u16* x5 = (u16*)(wsB + o_x5);
    u16* mein = (u16*)(wsB + o_mein);
    u16* m1 = (u16*)(wsB + o_m1); u16* m2 = (u16*)(wsB + o_m2);
    u16* hx = (u16*)(wsB + o_hx); u16* hx2 = (u16*)(wsB + o_hx2);
    u16* h2bf = (u16*)(wsB + o_h2bf);  u16* s1b = (u16*)(wsB + o_s1b);
    float* hst = (float*)(wsB + o_hst); float* h1f = (float*)(wsB + o_h1f);
    float* zf = (float*)(wsB + o_zf);
    float* s2 = (float*)(wsB + o_s2);

    float* outH = (float*)d_out;
    float* outFlow = outH + (long)2 * 128 * HWW;

    auto nb = [](long total, int bs) { return (unsigned)((total + bs - 1) / bs); };

    // ---- weight preps ----
    hipMemsetAsync(wsB, 0, wArenaBytes, stream);
    hipMemsetAsync(wsB + o_cvolT, 0, (size_t)12288 * 64 * 2, stream);

    WJobs J;
    {
        auto mk = [](const float* src, size_t dstOffBytes, int OC, int rowOff, int IC, int ICP, int NT) {
            WJob w; w.src = src; w.dstOff = dstOffBytes / 2; w.OC = OC; w.rowOff = rowOff;
            w.IC = IC; w.ICP = ICP; w.NT = NT; w.cum = 0; return w;
        };
        J.j[0]  = mk(mn_w1, o_wc1, 96, 0, 64, 64, 9);
        J.j[1]  = mk(mn_w2, o_wc2, 128, 0, 96, 96, 9);
        J.j[2]  = mk(mn_w3, o_wc3, 128, 0, 128, 128, 9);
        J.j[3]  = mk(mn_w4, o_wc4, 64, 0, 128, 128, 9);
        J.j[4]  = mk(me_w1, o_wme1, 128, 0, 83, 96, 9);
        J.j[5]  = mk(me_w2, o_wme2, 128, 0, 128, 128, 9);
        J.j[6]  = mk(me_w3, o_wme3, 94, 0, 128, 128, 9);
        J.j[7]  = mk(gz1_w, o_wzr1, 128, 0, 224, 224, 5);
        J.j[8]  = mk(gr1_w, o_wzr1, 128, 128, 224, 224, 5);
        J.j[9]  = mk(gq1_w, o_wq1, 128, 0, 224, 224, 5);
        J.j[10] = mk(gz2_w, o_wzr2, 128, 0, 224, 224, 5);
        J.j[11] = mk(gr2_w, o_wzr2, 128, 128, 224, 224, 5);
        J.j[12] = mk(gq2_w, o_wq2, 128, 0, 224, 224, 5);
        J.j[13] = mk(fh_w1, o_wfh1, 256, 0, 128, 128, 1);
        J.j[14] = mk(fh_w2, o_wfh2, 49, 0, 256, 256, 1);
        J.j[15] = mk(dap_w, o_wdapb, 49, 0, 49, 64, 1);
        long cum = 0;
        for (int k = 0; k < 16; ++k) {
            J.j[k].cum = cum;
            cum += (long)J.j[k].OC * J.j[k].NT * J.j[k].ICP;
        }
        J.total = cum;
    }
    k_wt_all<<<nb(J.total, 256), 256, 0, stream>>>(J, wbase);
    k_wt_dq<<<nb(32768, 256), 256, 0, stream>>>(mn_wd, wdq);
    k_wt5<<<2, 256, 0, stream>>>(mn_w5, w5t);
    k_catb<<<1, 256, 0, stream>>>(gz1_b, gr1_b, bzr1);
    k_catb<<<1, 256, 0, stream>>>(gz2_b, gr2_b, bzr2);

    // ---- input preps ----
    k_prep_f1<<<nb(24576, 256), 256, 0, stream>>>(fmap1, f1bf);
    k_warp<<<nb(24576, 256), 256, 0, stream>>>(fmap2, flow, f2wb, cs);

    // ---- matching net: conv1/conv2 in 2 chunks of 49; conv3+ once at full 98; BM=256 ----
    for (int n0 = 0; n0 < 98; n0 += CH) {
        k_gemm<256,96,1,3,3,1,1,1,1,0,64,96,64,96,32,18><<<dim3(1176, 1), 256, 0, stream>>>(
            f1bf, f2wb, cs, wc1, mn_b1, zpg, x1, nullptr, nullptr, 96, 96, 0, n0);
        k_gemm<256,128,0,3,3,1,1,2,1,0,64,96,32,48,96,27><<<dim3(294, 1), 256, 0, stream>>>(
            x1, nullptr, nullptr, wc2, mn_b2, zpg, x2 + (long)n0 * 196608, nullptr, nullptr, 128, 128, 0, 0);
    }
    k_gemm<256,128,0,3,3,1,1,1,1,0,32,48,32,48,128,36><<<dim3(588, 1), 256, 0, stream>>>(
        x2, nullptr, nullptr, wc3, mn_b3, zpg, x3, nullptr, nullptr, 128, 128, 0, 0);
    k_gemm<256,64,0,3,3,1,1,1,1,0,32,48,32,48,128,36><<<dim3(588, 1), 256, 0, stream>>>(
        x3, nullptr, nullptr, wc4, mn_b4, zpg, x4, nullptr, nullptr, 64, 64, 0, 0);
    k_gemm<128,32,2,4,4,2,2,1,1,0,32,48,32,48,64,8><<<dim3(1176, 1, 4), 256, 0, stream>>>(
        x4, nullptr, nullptr, wdq, mn_bd, zpg, x5, nullptr, nullptr, 32, 32, 0, 0);
    k_conv5n<<<nb(98L * HWW, 256), 256, 0, stream>>>(x5, w5t, mn_b5, cvolT, 98, 0);

    // ---- DAP (MFMA GEMM, BM=64) + me tail ----
    k_gemm<64,64,0,1,1,0,0,1,0,0,64,96,64,96,64,2><<<dim3(192, 1), 256, 0, stream>>>(
        cvolT, nullptr, nullptr, wdapb, dap_b, zpg, mein, nullptr, nullptr, 49, 96, 0, 0);
    k_me_tail<<<nb(73728, 256), 256, 0, stream>>>(fmap1, flow, mein);

    // ---- motion encoder (BM=64) ----
    k_gemm<64,128,0,3,3,1,1,1,2,0,64,96,64,96,96,27><<<dim3(192, 1), 256, 0, stream>>>(
        mein, nullptr, nullptr, wme1, me_b1, zpg, m1, nullptr, nullptr, 128, 128, 0, 0);
    k_gemm<64,128,0,3,3,1,1,1,2,0,64,96,64,96,128,36><<<dim3(192, 1), 256, 0, stream>>>(
        m1, nullptr, nullptr, wme2, me_b2, zpg, m2, nullptr, nullptr, 128, 128, 0, 0);
    k_gemm<64,96,0,3,3,1,1,1,0,0,64,96,64,96,128,36><<<dim3(192, 1), 256, 0, stream>>>(
        m2, nullptr, nullptr, wme3, me_b3, zpg, hx, hx2, nullptr, 94, 224, 128, 0);

    // ---- GRU 1 (horizontal 1x5; zr + q with fused epilogues) ----
    k_set_head<<<nb(49152, 256), 256, 0, stream>>>(h, flow, hst, hx, hx2);
    k_gemm<64,128,0,1,5,0,2,1,0,2,64,96,64,96,224,35><<<dim3(192, 2), 256, 0, stream>>>(
        hx, nullptr, hst, wzr1, bzr1, zpg, hx2, nullptr, zf, 256, 256, 0, 0);
    k_gemm<64,128,0,1,5,0,2,1,0,3,64,96,64,96,224,35><<<dim3(192, 1), 256, 0, stream>>>(
        hx2, (const u16*)zf, hst, wq1, gq1_b, zpg, hx, nullptr, h1f, 128, 128, 0, 0);

    // ---- GRU 2 (vertical 5x1) ----
    k_gemm<64,128,0,5,1,2,0,1,0,2,64,96,64,96,224,35><<<dim3(192, 2), 256, 0, stream>>>(
        hx, nullptr, h1f, wzr2, bzr2, zpg, hx2, nullptr, zf, 256, 256, 0, 0);
    k_gemm<64,128,0,5,1,2,0,1,0,4,64,96,64,96,224,35><<<dim3(192, 1), 256, 0, stream>>>(
        hx2, (const u16*)zf, h1f, wq2, gq2_b, zpg, h2bf, nullptr, outH, 128, 128, 0, 0);

    // ---- flow head ----
    k_gemm<64,128,0,1,1,0,0,1,2,0,64,96,64,96,128,4><<<dim3(192, 2), 256, 0, stream>>>(
        h2bf, nullptr, nullptr, wfh1, fh_b1, zpg, s1b, nullptr, nullptr, 256, 256, 0, 0);
    k_gemm<64,64,0,1,1,0,0,1,2,1,64,96,64,96,256,8><<<dim3(192, 1), 256, 0, stream>>>(
        s1b, nullptr, nullptr, wfh2, fh_b2, zpg, nullptr, nullptr, s2, 49, 64, 0, 0);
    k_soft<<<nb(12288, 256), 256, 0, stream>>>(s2, flow, outFlow);
}

// Round 18
// 657.502 us; speedup vs baseline: 1.2897x; 1.2897x over previous
//
#include <hip/hip_runtime.h>
#include <math.h>

typedef unsigned short u16;
typedef unsigned int u32;
typedef __attribute__((ext_vector_type(8))) short bf16x8;
typedef __attribute__((ext_vector_type(4))) float f32x4;

#define HWW 6144

__device__ __forceinline__ float sigmoidf_(float x) { return 1.f / (1.f + expf(-x)); }
__device__ __forceinline__ float lrelu_(float x) { return x >= 0.f ? x : 0.01f * x; }
__device__ __forceinline__ u16 f2bf(float f) {
    u32 u = __float_as_uint(f);
    u += 0x7fffu + ((u >> 16) & 1u);
    return (u16)(u >> 16);
}
__device__ __forceinline__ float bf2f(u16 h) { return __uint_as_float(((u32)h) << 16); }
__device__ __forceinline__ u32 pk2(float a, float b) { return (u32)f2bf(a) | ((u32)f2bf(b) << 16); }

// async global->LDS DMA: per-lane global src, wave-uniform LDS base + lane*16
__device__ __forceinline__ void gload_lds16(const u16* g, u16* l) {
    __builtin_amdgcn_global_load_lds((const __attribute__((address_space(1))) void*)g,
                                     (__attribute__((address_space(3))) void*)l, 16, 0, 0);
}

template<int N> __device__ __forceinline__ void waitcnt_vm() {
    if constexpr (N == 0) asm volatile("s_waitcnt vmcnt(0)" ::: "memory");
    else if constexpr (N == 2) asm volatile("s_waitcnt vmcnt(2)" ::: "memory");
    else if constexpr (N == 3) asm volatile("s_waitcnt vmcnt(3)" ::: "memory");
    else if constexpr (N == 4) asm volatile("s_waitcnt vmcnt(4)" ::: "memory");
    else if constexpr (N == 5) asm volatile("s_waitcnt vmcnt(5)" ::: "memory");
    else if constexpr (N == 6) asm volatile("s_waitcnt vmcnt(6)" ::: "memory");
    else asm volatile("s_waitcnt vmcnt(0)" ::: "memory");
}
__device__ __forceinline__ void barrier_raw() {
    asm volatile("" ::: "memory");
    __builtin_amdgcn_s_barrier();
    asm volatile("" ::: "memory");
}

// ======== fused weight transpose (16 jobs in one launch) ========
struct WJob { const float* src; unsigned long dstOff; int OC, rowOff, IC, ICP, NT; unsigned long cum; };
struct WJobs { WJob j[16]; long total; };

__global__ __launch_bounds__(256) void k_wt_all(WJobs J, u16* __restrict__ base)
{
    long i = (long)blockIdx.x * 256 + threadIdx.x;
    if (i >= J.total) return;
    int jb = 0;
    #pragma unroll
    for (int k = 1; k < 16; ++k) if (i >= (long)J.j[k].cum) jb = k;
    WJob w = J.j[jb];
    long local = i - (long)w.cum;
    int c = (int)(local % w.ICP);
    int t = (int)((local / w.ICP) % w.NT);
    int o = (int)(local / ((long)w.ICP * w.NT));
    float val = (c < w.IC) ? w.src[((long)o * w.IC + c) * w.NT + t] : 0.f;
    base[w.dstOff + ((long)(w.rowOff + o) * w.NT + t) * w.ICP + c] = f2bf(val);
}

__global__ __launch_bounds__(256) void k_wt_dq(const float* __restrict__ w, u16* __restrict__ dst)
{
    int i = blockIdx.x * 256 + threadIdx.x;
    if (i >= 32768) return;
    int c = i & 63; int t = (i >> 6) & 3; int o = (i >> 8) & 31; int q = i >> 13;
    int ry = q >> 1, rx = q & 1, ta = t >> 1, tb = t & 1;
    int ky = ry + 2 * ta, kx = rx + 2 * tb;
    float val = w[(((long)o * 64 + c) * 4 + ky) * 4 + kx];
    dst[(long)q * 8192 + o * 256 + t * 64 + c] = f2bf(val);
}

__global__ __launch_bounds__(256) void k_wt5(const float* __restrict__ w, float* __restrict__ wt)
{
    int i = blockIdx.x * 256 + threadIdx.x;
    if (i >= 288) return;
    int t = i % 9, c = i / 9;
    wt[t * 32 + c] = w[c * 9 + t];
}

__global__ void k_catb(const float* __restrict__ a, const float* __restrict__ b, float* __restrict__ d)
{
    int i = threadIdx.x;
    if (i < 128) d[i] = a[i];
    else if (i < 256) d[i] = b[i - 128];
}

// ======== elementwise / prep kernels ========
__global__ __launch_bounds__(256) void k_prep_f1(const float* __restrict__ fmap1, u16* __restrict__ f1bf)
{
    int gid = blockIdx.x * 256 + threadIdx.x;
    if (gid >= 24576) return;
    int idx = gid >> 1, half = gid & 1;
    int b = idx / HWW, p = idx % HWW;
    const float* fb = fmap1 + (long)b * 32 * HWW + p + (long)(half * 16) * HWW;
    u32 pk[8];
    #pragma unroll
    for (int c2 = 0; c2 < 8; ++c2)
        pk[c2] = pk2(fb[(long)(2 * c2) * HWW], fb[(long)(2 * c2 + 1) * HWW]);
    u16* op = f1bf + ((long)idx << 5) + half * 16;
    ((uint4*)op)[0] = make_uint4(pk[0], pk[1], pk[2], pk[3]);
    ((uint4*)op)[1] = make_uint4(pk[4], pk[5], pk[6], pk[7]);
}

__global__ __launch_bounds__(256) void k_warp(const float* __restrict__ fmap2, const float* __restrict__ flow,
                                              u16* __restrict__ f2wbf, float* __restrict__ cs)
{
    int gid = blockIdx.x * 256 + threadIdx.x;
    if (gid >= 24576) return;
    int idx = gid >> 1, half = gid & 1;
    int b = idx / HWW, p = idx % HWW, y = p / 96, x = p % 96;
    float u = flow[(b * 2 + 0) * HWW + p], v = flow[(b * 2 + 1) * HWW + p];
    float fx = (float)x + u, fy = (float)y + v;
    float fx0 = floorf(fx), fy0 = floorf(fy);
    float wx = fx - fx0, wy = fy - fy0;
    int x0 = (int)fx0, y0i = (int)fy0, x1 = x0 + 1, y1 = y0i + 1;
    bool vx0 = x0 >= 0 && x0 < 96, vx1 = x1 >= 0 && x1 < 96;
    bool vy0 = y0i >= 0 && y0i < 64, vy1 = y1 >= 0 && y1 < 64;
    float m00 = (vy0 && vx0) ? (1.f - wy) * (1.f - wx) : 0.f;
    float m01 = (vy0 && vx1) ? (1.f - wy) * wx : 0.f;
    float m10 = (vy1 && vx0) ? wy * (1.f - wx) : 0.f;
    float m11 = (vy1 && vx1) ? wy * wx : 0.f;
    int cx0 = min(max(x0, 0), 95), cx1 = min(max(x1, 0), 95);
    int cy0 = min(max(y0i, 0), 63), cy1 = min(max(y1, 0), 63);
    int i00 = cy0 * 96 + cx0, i01 = cy0 * 96 + cx1, i10 = cy1 * 96 + cx0, i11 = cy1 * 96 + cx1;
    const float* fb = fmap2 + (long)b * 32 * HWW + (long)(half * 16) * HWW;
    float s = 0.f; u32 pk[8];
    #pragma unroll
    for (int c2 = 0; c2 < 8; ++c2) {
        const float* fa = fb + (long)(2 * c2) * HWW;
        const float* fc = fb + (long)(2 * c2 + 1) * HWW;
        float g0 = m00 * fa[i00] + m01 * fa[i01] + m10 * fa[i10] + m11 * fa[i11];
        float g1 = m00 * fc[i00] + m01 * fc[i01] + m10 * fc[i10] + m11 * fc[i11];
        s += g0 + g1;
        pk[c2] = pk2(g0, g1);
    }
    u16* op = f2wbf + ((long)idx << 5) + half * 16;
    ((uint4*)op)[0] = make_uint4(pk[0], pk[1], pk[2], pk[3]);
    ((uint4*)op)[1] = make_uint4(pk[4], pk[5], pk[6], pk[7]);
    float stot = s + __shfl_xor(s, 1);
    if (half == 0) cs[idx] = stot;
}

// ======== MFMA implicit GEMM: DMA staging, 3-buffer LDS, 1-barrier counted-vmcnt phase ========
// BM: 128/64. BN: 128/96/64/32. MODE 0: conv NHWC; 1: conv1 mvol; 2: deconv quad (blockIdx.z)
// OUTF32: 0 bf16 out (+outb2), 1 f32 out, 2 GRU zr fuse, 3 GRU q fuse (mid), 4 GRU q fuse (final)
template<int BM, int BN, int MODE, int KH, int KW, int PH, int PW, int STRIDE, int ACT, int OUTF32,
         int IH, int IW, int OH, int OW, int ICP, int NKT>
__global__ __launch_bounds__(256) void k_gemm(
    const u16* __restrict__ A0, const u16* __restrict__ A1,
    const float* __restrict__ csm, const u16* __restrict__ Wb,
    const float* __restrict__ bias, const u16* __restrict__ zpg,
    u16* __restrict__ outb, u16* __restrict__ outb2, float* __restrict__ outf,
    int OC, int ldc, int coff, int nOff)
{
    constexpr int WAVES_N = (BN >= 128) ? 2 : 1;
    constexpr int WAVES_M = 4 / WAVES_N;
    constexpr int WTM = BM / WAVES_M;
    constexpr int WTN = BN / WAVES_N;
    constexpr int MF = WTM / 16;
    constexpr int NF = WTN / 16;
    __shared__ u16 As[3][BM * 32];
    __shared__ u16 Bs[3][BN * 32];
    __shared__ u16 dmy[512];
    int tid = threadIdx.x, lane = tid & 63, wid = tid >> 6;
    constexpr int AIW = BM / 64;            // A DMA instrs per wave
    constexpr int BG  = BN / 16;            // B 16-row groups
    constexpr int BJW = (BG + 3) / 4;       // B DMA slots per wave (uniform; invalid -> dummy)
    constexpr int LPS = AIW + BJW;          // DMA instrs per lane per stage (uniform)
    int ryz = 0, rxz = 0;
    if (MODE == 2) { ryz = blockIdx.z >> 1; rxz = blockIdx.z & 1; }
    const u16* WbZ = Wb + (MODE == 2 ? (long)blockIdx.z * 32 * 256 : 0);
    int n0 = blockIdx.y * BN;
    int chunk = lane & 3, sub = lane >> 2;

    // ---- per-lane A staging state (AIW rows per lane, decoded once) ----
    const u16* aB0[AIW]; const u16* aB1[AIW]; u32 am[AIW];
    #pragma unroll
    for (int j = 0; j < AIW; ++j) {
        int row = wid * (BM / 4) + j * 16 + sub;
        int gm = blockIdx.x * BM + row;
        constexpr int OHW = (MODE == 1) ? 6144 : ((MODE == 2) ? 1536 : OH * OW);
        constexpr int OWW = (MODE == 1) ? 96 : ((MODE == 2) ? 48 : OW);
        int nI = gm / OHW, rem = gm - nI * OHW;
        int y0 = rem / OWW, x0 = rem - y0 * OWW;
        aB1[j] = A0; am[j] = 0;
        if (MODE == 0) {
            aB0[j] = A0 + ((long)nI * IH * IW + (long)y0 * STRIDE * IW + (long)x0 * STRIDE) * ICP + chunk * 8;
            u32 m = 0;
            #pragma unroll
            for (int t = 0; t < KH * KW; ++t) {
                int dy = t / KW - PH, dx = t % KW - PW;
                int iy = y0 * STRIDE + dy, ix = x0 * STRIDE + dx;
                m |= ((iy >= 0 && iy < IH && ix >= 0 && ix < IW) ? 1u : 0u) << t;
            }
            am[j] = m;
        } else if (MODE == 1) {
            int n = nOff + nI, bI = n / 49, kd = n - bI * 49;
            int di = kd / 7 - 3, dj = kd % 7 - 3;
            long bH = (long)bI * 6144;
            aB0[j] = A0 + ((bH + rem) << 5) + chunk * 8;
            aB1[j] = A1 + ((bH + (y0 + dj) * 96 + (x0 + di)) << 5) + chunk * 8;
            u32 m = 0;
            #pragma unroll
            for (int t = 0; t < 9; ++t) {
                int dy = t / 3 - 1, dx = t % 3 - 1;
                int yy = y0 + dy, xx = x0 + dx, ys = yy + dj, xs = xx + di;
                bool v = yy >= 0 && yy < 64 && xx >= 0 && xx < 96 && ys >= 0 && ys < 64 && xs >= 0 && xs < 96;
                if (v) v = (csm[bI * 6144 + ys * 96 + xs] != 0.f);
                m |= (v ? 1u : 0u) << t;
            }
            am[j] = m;
        } else {
            int iy0 = y0 + ryz - 1, ix0 = x0 + rxz - 1;
            aB0[j] = A0 + ((long)nI * 1536 + (long)iy0 * 48 + ix0) * 64 + chunk * 8;
            u32 m = 0;
            #pragma unroll
            for (int t = 0; t < 4; ++t) {
                int ta = t >> 1, tb = t & 1;
                int iy = iy0 + ta, ix = ix0 + tb;
                m |= ((iy >= 0 && iy < 32 && ix >= 0 && ix < 48) ? 1u : 0u) << t;
            }
            am[j] = m;
        }
    }
    // ---- per-lane B staging state: wave w stages 16-row groups g = w + 4j ----
    const u16* bB[BJW];
    #pragma unroll
    for (int j = 0; j < BJW; ++j) {
        int g = wid + 4 * j;
        int gc = (g < BG) ? g : 0;
        bB[j] = WbZ + (long)(n0 + gc * 16 + sub) * (NKT * 32) + chunk * 8;
    }

    auto stage = [&](int kt, int bn) {
        #pragma unroll
        for (int j = 0; j < AIW; ++j) {
            const u16* g;
            if (MODE == 0) {
                constexpr int KTC = ICP / 32;
                int t = kt / KTC, c0 = (kt - t * KTC) << 5;
                int dy = t / KW - PH, dx = t % KW - PW;
                bool v = (am[j] >> t) & 1u;
                g = v ? aB0[j] + (long)(dy * IW + dx) * ICP + c0 : zpg;
            } else if (MODE == 1) {
                int t = kt >> 1, half = kt & 1;
                int dy = t / 3 - 1, dx = t % 3 - 1;
                bool v = (am[j] >> t) & 1u;
                const u16* b = half ? aB1[j] : aB0[j];
                g = v ? b + ((dy * 96 + dx) << 5) : zpg;
            } else {
                int t = kt >> 1, c0 = (kt & 1) << 5;
                int ta = t >> 1, tb = t & 1;
                bool v = (am[j] >> t) & 1u;
                g = v ? aB0[j] + (ta * 48 + tb) * 64 + c0 : zpg;
            }
            gload_lds16(g, &As[bn][(wid * (BM / 4) + j * 16) * 32]);
        }
        #pragma unroll
        for (int j = 0; j < BJW; ++j) {
            int g = wid + 4 * j;
            if (g < BG) gload_lds16(bB[j] + kt * 32, &Bs[bn][g * 512]);
            else gload_lds16(zpg, dmy);
        }
    };

    int wm = (WAVES_N == 2) ? (wid >> 1) : wid;
    int wn = (WAVES_N == 2) ? (wid & 1) : 0;
    int fr = lane & 15, fg = lane >> 4;
    f32x4 acc[MF][NF];
    #pragma unroll
    for (int i = 0; i < MF; ++i)
        #pragma unroll
        for (int j = 0; j < NF; ++j)
            acc[i][j] = (f32x4){0.f, 0.f, 0.f, 0.f};

    // prologue: stage kt=0,1 into buffers 0,1; wait for kt=0 only (kt=1 stays in flight)
    stage(0, 0);
    if (NKT > 1) stage(1, 1);
    if (NKT > 1) waitcnt_vm<LPS>(); else waitcnt_vm<0>();
    barrier_raw();

    // one-barrier phase: stage(kt+2) | MFMA(kt) | waitcnt(kt+1 landed) | barrier
    #pragma unroll
    for (int kt = 0; kt < NKT; ++kt) {
        int cur = kt % 3;
        if (kt + 2 < NKT) stage(kt + 2, (kt + 2) % 3);
        bf16x8 af[MF], bv[NF];
        #pragma unroll
        for (int i = 0; i < MF; ++i)
            af[i] = *(const bf16x8*)&As[cur][(wm * WTM + i * 16 + fr) * 32 + fg * 8];
        #pragma unroll
        for (int j = 0; j < NF; ++j)
            bv[j] = *(const bf16x8*)&Bs[cur][(wn * WTN + j * 16 + fr) * 32 + fg * 8];
        #pragma unroll
        for (int i = 0; i < MF; ++i)
            #pragma unroll
            for (int j = 0; j < NF; ++j)
                acc[i][j] = __builtin_amdgcn_mfma_f32_16x16x32_bf16(af[i], bv[j], acc[i][j], 0, 0, 0);
        if (kt + 1 < NKT) {
            if (kt + 2 < NKT) waitcnt_vm<LPS>();   // kt+1's DMAs done; kt+2's stay in flight
            else waitcnt_vm<0>();                  // tail: drain kt+1
            barrier_raw();                         // kt+1 data visible to all waves
        }
    }

    // epilogue
    #pragma unroll
    for (int i = 0; i < MF; ++i) {
        #pragma unroll
        for (int j = 0; j < NF; ++j) {
            int nn = n0 + wn * WTN + j * 16 + fr;
            if (nn >= OC) continue;
            #pragma unroll
            for (int rr = 0; rr < 4; ++rr) {
                int mloc = wm * WTM + i * 16 + fg * 4 + rr;
                long gm = (long)blockIdx.x * BM + mloc;
                float v = acc[i][j][rr] + bias[nn];
                if (ACT == 1) v = fmaxf(v, 0.f);
                else if (ACT == 2) v = lrelu_(v);
                if (OUTF32 == 1) {
                    outf[gm * ldc + coff + nn] = v;
                } else if (OUTF32 == 2) {
                    float s = sigmoidf_(v);
                    if (nn < 128) outf[gm * 128 + nn] = s;
                    else outb[gm * 224 + (nn - 128)] = f2bf(s * csm[gm * 128 + (nn - 128)]);
                } else if (OUTF32 == 3 || OUTF32 == 4) {
                    float zv = ((const float*)A1)[gm * 128 + nn];
                    float hnew = (1.f - zv) * csm[gm * 128 + nn] + zv * tanhf(v);
                    if (OUTF32 == 3) {
                        outf[gm * 128 + nn] = hnew;
                        outb[gm * 224 + nn] = f2bf(hnew);
                    } else {
                        int bb = (int)(gm / 6144), pp = (int)(gm - (long)bb * 6144);
                        outf[((long)(bb * 128 + nn)) * 6144 + pp] = hnew;
                        outb[gm * 128 + nn] = f2bf(hnew);
                    }
                } else if (MODE == 2) {
                    int nI = (int)(gm / 1536); int rq = (int)(gm - (long)nI * 1536);
                    int Y = rq / 48, X = rq - (rq / 48) * 48;
                    long di = (((long)nI * 64 + 2 * Y + ryz) * 96 + (2 * X + rxz)) * 32 + nn;
                    outb[di] = f2bf(v);
                } else {
                    long di = gm * ldc + coff + nn;
                    u16 hv = f2bf(v);
                    outb[di] = hv;
                    if (outb2) outb2[di] = hv;
                }
            }
        }
    }
}

// ======== conv5 (32->1, 3x3) scalar over NHWC bf16 -> cvolT [b][p][64] bf16 ========
__global__ __launch_bounds__(256) void k_conv5n(const u16* __restrict__ x5, const float* __restrict__ w5t,
                                                const float* __restrict__ b5, u16* __restrict__ cvolT,
                                                int N, int n0)
{
    int idx = blockIdx.x * 256 + threadIdx.x;
    if (idx >= N * HWW) return;
    int nl = idx / HWW, p = idx % HWW, y = p / 96, x = p % 96;
    float acc = b5[0];
    #pragma unroll
    for (int t = 0; t < 9; ++t) {
        int iy = y + t / 3 - 1, ix = x + t % 3 - 1;
        if (iy < 0 || iy >= 64 || ix < 0 || ix >= 96) continue;
        const u16* sp = x5 + (((long)nl * HWW + iy * 96 + ix) << 5);
        const float* wt_ = w5t + t * 32;
        #pragma unroll
        for (int c8 = 0; c8 < 4; ++c8) {
            uint4 v = *(const uint4*)(sp + c8 * 8);
            acc = fmaf(bf2f((u16)(v.x & 0xffffu)), wt_[c8 * 8 + 0], acc);
            acc = fmaf(bf2f((u16)(v.x >> 16)),     wt_[c8 * 8 + 1], acc);
            acc = fmaf(bf2f((u16)(v.y & 0xffffu)), wt_[c8 * 8 + 2], acc);
            acc = fmaf(bf2f((u16)(v.y >> 16)),     wt_[c8 * 8 + 3], acc);
            acc = fmaf(bf2f((u16)(v.z & 0xffffu)), wt_[c8 * 8 + 4], acc);
            acc = fmaf(bf2f((u16)(v.z >> 16)),     wt_[c8 * 8 + 5], acc);
            acc = fmaf(bf2f((u16)(v.w & 0xffffu)), wt_[c8 * 8 + 6], acc);
            acc = fmaf(bf2f((u16)(v.w >> 16)),     wt_[c8 * 8 + 7], acc);
        }
    }
    int n = n0 + nl;
    int b = n / 49, k = n - b * 49;
    cvolT[((long)b * HWW + p) * 64 + k] = f2bf(acc);
}

// ======== mein ch 49..95 (fmap1, flow, zero-pad); 6-way channel split ========
__global__ __launch_bounds__(256) void k_me_tail(const float* __restrict__ fmap1, const float* __restrict__ flow,
                                                 u16* __restrict__ mein)
{
    int gid = blockIdx.x * 256 + threadIdx.x;
    if (gid >= 73728) return;
    int j = gid / 12288, idx = gid - j * 12288;
    int b = idx / HWW, p = idx % HWW;
    int c0 = 49 + j * 8;
    u16* mp = mein + (long)idx * 96;
    #pragma unroll
    for (int q = 0; q < 8; ++q) {
        int c = c0 + q;
        if (c >= 96) break;
        float v;
        if (c < 81) v = fmap1[((long)(b * 32 + (c - 49))) * HWW + p];
        else if (c == 81) v = flow[(b * 2 + 0) * HWW + p];
        else if (c == 82) v = flow[(b * 2 + 1) * HWW + p];
        else v = 0.f;
        mp[c] = f2bf(v);
    }
}

// ======== set hx head from h (NCHW f32) + hst + flow tails; 4-way channel split ========
__global__ __launch_bounds__(256) void k_set_head(const float* __restrict__ h, const float* __restrict__ flow,
                                                  float* __restrict__ hst, u16* __restrict__ hx,
                                                  u16* __restrict__ hx2)
{
    int gid = blockIdx.x * 256 + threadIdx.x;
    if (gid >= 49152) return;
    int cq = gid / 12288, idx = gid - cq * 12288;
    int b = idx / HWW, p = idx % HWW;
    int c0 = cq * 32;
    const float* hp = h + (long)b * 128 * HWW + p;
    float* hs = hst + (long)idx * 128;
    u16* hxp = hx + (long)idx * 224;
    #pragma unroll
    for (int c = c0; c < c0 + 32; c += 8) {
        float v[8];
        #pragma unroll
        for (int q = 0; q < 8; ++q) v[q] = hp[(long)(c + q) * HWW];
        *(float4*)&hs[c] = make_float4(v[0], v[1], v[2], v[3]);
        *(float4*)&hs[c + 4] = make_float4(v[4], v[5], v[6], v[7]);
        uint4 pk = make_uint4(pk2(v[0], v[1]), pk2(v[2], v[3]), pk2(v[4], v[5]), pk2(v[6], v[7]));
        *(uint4*)&hxp[c] = pk;
    }
    if (cq == 0) {
        u16 uu = f2bf(flow[(b * 2 + 0) * HWW + p]);
        u16 vv = f2bf(flow[(b * 2 + 1) * HWW + p]);
        long o = (long)idx * 224;
        hx[o + 222] = uu; hx[o + 223] = vv;
        hx2[o + 222] = uu; hx2[o + 223] = vv;
    }
}

// ======== softmax + expectation + flow add ========
__global__ __launch_bounds__(256) void k_soft(const float* __restrict__ s2, const float* __restrict__ flow,
                                              float* __restrict__ outFlow)
{
    int idx = blockIdx.x * 256 + threadIdx.x;
    if (idx >= 12288) return;
    int b = idx / HWW, p = idx % HWW;
    const float* sp = s2 + (long)idx * 64;
    float lg[49];
    #pragma unroll
    for (int k = 0; k < 48; k += 4) {
        float4 v = *(const float4*)&sp[k];
        lg[k] = v.x; lg[k + 1] = v.y; lg[k + 2] = v.z; lg[k + 3] = v.w;
    }
    lg[48] = sp[48];
    float m = -1e30f;
    #pragma unroll
    for (int k = 0; k < 49; ++k) m = fmaxf(m, lg[k]);
    float s = 0.f, a0 = 0.f, a1 = 0.f;
    #pragma unroll
    for (int k = 0; k < 49; ++k) {
        float e = expf(lg[k] - m);
        s += e;
        a0 += e * (float)(k / 7 - 3);
        a1 += e * (float)(k % 7 - 3);
    }
    float inv = 1.f / s;
    outFlow[(long)(b * 2 + 0) * HWW + p] = flow[(long)(b * 2 + 0) * HWW + p] + a0 * inv;
    outFlow[(long)(b * 2 + 1) * HWW + p] = flow[(long)(b * 2 + 1) * HWW + p] + a1 * inv;
}

extern "C" void kernel_launch(void* const* d_in, const int* in_sizes, int n_in,
                              void* d_out, int out_size, void* d_ws, size_t ws_size,
                              hipStream_t stream)
{
    const float* fmap1 = (const float*)d_in[0];
    const float* fmap2 = (const float*)d_in[1];
    const float* h     = (const float*)d_in[2];
    const float* flow  = (const float*)d_in[3];
    int pb = (in_sizes[4] == 1) ? 5 : 4;
    const float* mn_w1 = (const float*)d_in[pb + 0];
    const float* mn_b1 = (const float*)d_in[pb + 1];
    const float* mn_w2 = (const float*)d_in[pb + 2];
    const float* mn_b2 = (const float*)d_in[pb + 3];
    const float* mn_w3 = (const float*)d_in[pb + 4];
    const float* mn_b3 = (const float*)d_in[pb + 5];
    const float* mn_w4 = (const float*)d_in[pb + 6];
    const float* mn_b4 = (const float*)d_in[pb + 7];
    const float* mn_wd = (const float*)d_in[pb + 8];
    const float* mn_bd = (const float*)d_in[pb + 9];
    const float* mn_w5 = (const float*)d_in[pb + 10];
    const float* mn_b5 = (const float*)d_in[pb + 11];
    const float* dap_w = (const float*)d_in[pb + 12];
    const float* dap_b = (const float*)d_in[pb + 13];
    const float* me_w1 = (const float*)d_in[pb + 14];
    const float* me_b1 = (const float*)d_in[pb + 15];
    const float* me_w2 = (const float*)d_in[pb + 16];
    const float* me_b2 = (const float*)d_in[pb + 17];
    const float* me_w3 = (const float*)d_in[pb + 18];
    const float* me_b3 = (const float*)d_in[pb + 19];
    const float* gz1_w = (const float*)d_in[pb + 20];
    const float* gz1_b = (const float*)d_in[pb + 21];
    const float* gr1_w = (const float*)d_in[pb + 22];
    const float* gr1_b = (const float*)d_in[pb + 23];
    const float* gq1_w = (const float*)d_in[pb + 24];
    const float* gq1_b = (const float*)d_in[pb + 25];
    const float* gz2_w = (const float*)d_in[pb + 26];
    const float* gz2_b = (const float*)d_in[pb + 27];
    const float* gr2_w = (const float*)d_in[pb + 28];
    const float* gr2_b = (const float*)d_in[pb + 29];
    const float* gq2_w = (const float*)d_in[pb + 30];
    const float* gq2_b = (const float*)d_in[pb + 31];
    const float* fh_w1 = (const float*)d_in[pb + 32];
    const float* fh_b1 = (const float*)d_in[pb + 33];
    const float* fh_w2 = (const float*)d_in[pb + 34];
    const float* fh_b2 = (const float*)d_in[pb + 35];

    char* wsB = (char*)d_ws;
    size_t off = 0;
    auto alc = [&](size_t bytes) { size_t o = off; off = (off + bytes + 255) & ~(size_t)255; return o; };

    // ---- weight arena (memset to 0 first; includes zero-page) ----
    size_t o_zpg  = alc(256);
    size_t o_wc1  = alc(128 * 576 * 2);
    size_t o_wc2  = alc(128 * 864 * 2);
    size_t o_wc3  = alc((size_t)128 * 1152 * 2);
    size_t o_wc4  = alc((size_t)64 * 1152 * 2);
    size_t o_wdq  = alc(32768 * 2);
    size_t o_wme1 = alc(128 * 864 * 2);
    size_t o_wme2 = alc((size_t)128 * 1152 * 2);
    size_t o_wme3 = alc((size_t)128 * 1152 * 2);
    size_t o_wzr1 = alc((size_t)256 * 1120 * 2);
    size_t o_wq1  = alc((size_t)128 * 1120 * 2);
    size_t o_wzr2 = alc((size_t)256 * 1120 * 2);
    size_t o_wq2  = alc((size_t)128 * 1120 * 2);
    size_t o_wfh1 = alc(256 * 128 * 2);
    size_t o_wfh2 = alc(64 * 256 * 2);
    size_t o_wdapb= alc(64 * 64 * 2);
    size_t o_w5t  = alc(288 * 4);
    size_t o_bzr1 = alc(256 * 4);
    size_t o_bzr2 = alc(256 * 4);
    size_t wArenaBytes = off;

    // ---- persistent activations ----
    size_t o_f1bf = alc((size_t)12288 * 32 * 2);
    size_t o_f2wb = alc((size_t)12288 * 32 * 2);
    size_t o_cs   = alc(12288 * 4);
    size_t o_cvolT= alc((size_t)12288 * 64 * 2);

    // ---- shared region: phase-A x-scratch overlaid with phase-B buffers ----
    const int CH = 49;
    size_t sharedBase = off;
    size_t offA = sharedBase;
    auto alcA = [&](size_t bytes) { size_t o = offA; offA = (offA + bytes + 255) & ~(size_t)255; return o; };
    size_t o_x1 = alcA((size_t)CH * 6144 * 96 * 2);
    size_t o_x2 = alcA((size_t)98 * 1536 * 128 * 2);
    size_t o_x3 = alcA((size_t)98 * 1536 * 128 * 2);
    size_t o_x4 = alcA((size_t)98 * 1536 * 64 * 2);
    size_t o_x5 = alcA((size_t)98 * 6144 * 32 * 2);
    size_t offB2 = sharedBase;
    auto alcB = [&](size_t bytes) { size_t o = offB2; offB2 = (offB2 + bytes + 255) & ~(size_t)255; return o; };
    size_t o_mein = alcB((size_t)12288 * 96 * 2);
    size_t o_m1   = alcB((size_t)12288 * 128 * 2);
    size_t o_m2   = alcB((size_t)12288 * 128 * 2);
    size_t o_hx   = alcB((size_t)12288 * 224 * 2);
    size_t o_hx2  = alcB((size_t)12288 * 224 * 2);
    size_t o_h2bf = alcB((size_t)12288 * 128 * 2);
    size_t o_s1b  = alcB((size_t)12288 * 256 * 2);
    size_t o_hst  = alcB((size_t)12288 * 128 * 4);
    size_t o_h1f  = alcB((size_t)12288 * 128 * 4);
    size_t o_zf   = alcB((size_t)12288 * 128 * 4);
    size_t o_s2   = alcB((size_t)12288 * 64 * 4);

    u16* wbase = (u16*)wsB;
    u16* zpg  = (u16*)(wsB + o_zpg);
    u16* wdq  = (u16*)(wsB + o_wdq);
    float* w5t = (float*)(wsB + o_w5t);
    float* bzr1 = (float*)(wsB + o_bzr1);
    float* bzr2 = (float*)(wsB + o_bzr2);
    u16* wc1  = (u16*)(wsB + o_wc1);   u16* wc2  = (u16*)(wsB + o_wc2);
    u16* wc3  = (u16*)(wsB + o_wc3);   u16* wc4  = (u16*)(wsB + o_wc4);
    u16* wme1 = (u16*)(wsB + o_wme1);  u16* wme2 = (u16*)(wsB + o_wme2);
    u16* wme3 = (u16*)(wsB + o_wme3);
    u16* wzr1 = (u16*)(wsB + o_wzr1);  u16* wq1  = (u16*)(wsB + o_wq1);
    u16* wzr2 = (u16*)(wsB + o_wzr2);  u16* wq2  = (u16*)(wsB + o_wq2);
    u16* wfh1 = (u16*)(wsB + o_wfh1);  u16* wfh2 = (u16*)(wsB + o_wfh2);
    u16* wdapb= (u16*)(wsB + o_wdapb);

    u16* f1bf = (u16*)(wsB + o_f1bf);  u16* f2wb = (u16*)(wsB + o_f2wb);
    float* cs = (float*)(wsB + o_cs);
    u16* cvolT = (u16*)(wsB + o_cvolT);
    u16* x1 = (u16*)(wsB + o_x1); u16* x2 = (u16*)(wsB + o_x2); u16* x3 = (u16*)(wsB + o_x3);
    u16* x4 = (u16*)(wsB + o_x4); u16* x5 = (u16*)(wsB + o_x5);
    u16* mein = (u16*)(wsB + o_mein);
    u16* m1 = (u16*)(wsB + o_m1); u16* m2 = (u16*)(wsB + o_m2);
    u16* hx = (u16*)(wsB + o_hx); u16* hx2 = (u16*)(wsB + o_hx2);
    u16* h2bf = (u16*)(wsB + o_h2bf);  u16* s1b = (u16*)(wsB + o_s1b);
    float* hst = (float*)(wsB + o_hst); float* h1f = (float*)(wsB + o_h1f);
    float* zf = (float*)(wsB + o_zf);
    float* s2 = (float*)(wsB + o_s2);

    float* outH = (float*)d_out;
    float* outFlow = outH + (long)2 * 128 * HWW;

    auto nb = [](long total, int bs) { return (unsigned)((total + bs - 1) / bs); };

    // ---- weight preps ----
    hipMemsetAsync(wsB, 0, wArenaBytes, stream);
    hipMemsetAsync(wsB + o_cvolT, 0, (size_t)12288 * 64 * 2, stream);

    WJobs J;
    {
        auto mk = [](const float* src, size_t dstOffBytes, int OC, int rowOff, int IC, int ICP, int NT) {
            WJob w; w.src = src; w.dstOff = dstOffBytes / 2; w.OC = OC; w.rowOff = rowOff;
            w.IC = IC; w.ICP = ICP; w.NT = NT; w.cum = 0; return w;
        };
        J.j[0]  = mk(mn_w1, o_wc1, 96, 0, 64, 64, 9);
        J.j[1]  = mk(mn_w2, o_wc2, 128, 0, 96, 96, 9);
        J.j[2]  = mk(mn_w3, o_wc3, 128, 0, 128, 128, 9);
        J.j[3]  = mk(mn_w4, o_wc4, 64, 0, 128, 128, 9);
        J.j[4]  = mk(me_w1, o_wme1, 128, 0, 83, 96, 9);
        J.j[5]  = mk(me_w2, o_wme2, 128, 0, 128, 128, 9);
        J.j[6]  = mk(me_w3, o_wme3, 94, 0, 128, 128, 9);
        J.j[7]  = mk(gz1_w, o_wzr1, 128, 0, 224, 224, 5);
        J.j[8]  = mk(gr1_w, o_wzr1, 128, 128, 224, 224, 5);
        J.j[9]  = mk(gq1_w, o_wq1, 128, 0, 224, 224, 5);
        J.j[10] = mk(gz2_w, o_wzr2, 128, 0, 224, 224, 5);
        J.j[11] = mk(gr2_w, o_wzr2, 128, 128, 224, 224, 5);
        J.j[12] = mk(gq2_w, o_wq2, 128, 0, 224, 224, 5);
        J.j[13] = mk(fh_w1, o_wfh1, 256, 0, 128, 128, 1);
        J.j[14] = mk(fh_w2, o_wfh2, 49, 0, 256, 256, 1);
        J.j[15] = mk(dap_w, o_wdapb, 49, 0, 49, 64, 1);
        long cum = 0;
        for (int k = 0; k < 16; ++k) {
            J.j[k].cum = cum;
            cum += (long)J.j[k].OC * J.j[k].NT * J.j[k].ICP;
        }
        J.total = cum;
    }
    k_wt_all<<<nb(J.total, 256), 256, 0, stream>>>(J, wbase);
    k_wt_dq<<<nb(32768, 256), 256, 0, stream>>>(mn_wd, wdq);
    k_wt5<<<2, 256, 0, stream>>>(mn_w5, w5t);
    k_catb<<<1, 256, 0, stream>>>(gz1_b, gr1_b, bzr1);
    k_catb<<<1, 256, 0, stream>>>(gz2_b, gr2_b, bzr2);

    // ---- input preps ----
    k_prep_f1<<<nb(24576, 256), 256, 0, stream>>>(fmap1, f1bf);
    k_warp<<<nb(24576, 256), 256, 0, stream>>>(fmap2, flow, f2wb, cs);

    // ---- matching net: conv1/conv2 in 2 chunks of 49; conv3+ once at full 98 ----
    for (int n0 = 0; n0 < 98; n0 += CH) {
        k_gemm<128,96,1,3,3,1,1,1,1,0,64,96,64,96,32,18><<<dim3(2352, 1), 256, 0, stream>>>(
            f1bf, f2wb, cs, wc1, mn_b1, zpg, x1, nullptr, nullptr, 96, 96, 0, n0);
        k_gemm<128,128,0,3,3,1,1,2,1,0,64,96,32,48,96,27><<<dim3(588, 1), 256, 0, stream>>>(
            x1, nullptr, nullptr, wc2, mn_b2, zpg, x2 + (long)n0 * 196608, nullptr, nullptr, 128, 128, 0, 0);
    }
    k_gemm<128,128,0,3,3,1,1,1,1,0,32,48,32,48,128,36><<<dim3(1176, 1), 256, 0, stream>>>(
        x2, nullptr, nullptr, wc3, mn_b3, zpg, x3, nullptr, nullptr, 128, 128, 0, 0);
    k_gemm<128,64,0,3,3,1,1,1,1,0,32,48,32,48,128,36><<<dim3(1176, 1), 256, 0, stream>>>(
        x3, nullptr, nullptr, wc4, mn_b4, zpg, x4, nullptr, nullptr, 64, 64, 0, 0);
    k_gemm<128,32,2,4,4,2,2,1,1,0,32,48,32,48,64,8><<<dim3(1176, 1, 4), 256, 0, stream>>>(
        x4, nullptr, nullptr, wdq, mn_bd, zpg, x5, nullptr, nullptr, 32, 32, 0, 0);
    k_conv5n<<<nb(98L * HWW, 256), 256, 0, stream>>>(x5, w5t, mn_b5, cvolT, 98, 0);

    // ---- DAP (MFMA GEMM, BM=64) + me tail ----
    k_gemm<64,64,0,1,1,0,0,1,0,0,64,96,64,96,64,2><<<dim3(192, 1), 256, 0, stream>>>(
        cvolT, nullptr, nullptr, wdapb, dap_b, zpg, mein, nullptr, nullptr, 49, 96, 0, 0);
    k_me_tail<<<nb(73728, 256), 256, 0, stream>>>(fmap1, flow, mein);

    // ---- motion encoder (BM=64) ----
    k_gemm<64,128,0,3,3,1,1,1,2,0,64,96,64,96,96,27><<<dim3(192, 1), 256, 0, stream>>>(
        mein, nullptr, nullptr, wme1, me_b1, zpg, m1, nullptr, nullptr, 128, 128, 0, 0);
    k_gemm<64,128,0,3,3,1,1,1,2,0,64,96,64,96,128,36><<<dim3(192, 1), 256, 0, stream>>>(
        m1, nullptr, nullptr, wme2, me_b2, zpg, m2, nullptr, nullptr, 128, 128, 0, 0);
    k_gemm<64,96,0,3,3,1,1,1,0,0,64,96,64,96,128,36><<<dim3(192, 1), 256, 0, stream>>>(
        m2, nullptr, nullptr, wme3, me_b3, zpg, hx, hx2, nullptr, 94, 224, 128, 0);

    // ---- GRU 1 (horizontal 1x5; zr + q with fused epilogues) ----
    k_set_head<<<nb(49152, 256), 256, 0, stream>>>(h, flow, hst, hx, hx2);
    k_gemm<64,128,0,1,5,0,2,1,0,2,64,96,64,96,224,35><<<dim3(192, 2), 256, 0, stream>>>(
        hx, nullptr, hst, wzr1, bzr1, zpg, hx2, nullptr, zf, 256, 256, 0, 0);
    k_gemm<64,128,0,1,5,0,2,1,0,3,64,96,64,96,224,35><<<dim3(192, 1), 256, 0, stream>>>(
        hx2, (const u16*)zf, hst, wq1, gq1_b, zpg, hx, nullptr, h1f, 128, 128, 0, 0);

    // ---- GRU 2 (vertical 5x1) ----
    k_gemm<64,128,0,5,1,2,0,1,0,2,64,96,64,96,224,35><<<dim3(192, 2), 256, 0, stream>>>(
        hx, nullptr, h1f, wzr2, bzr2, zpg, hx2, nullptr, zf, 256, 256, 0, 0);
    k_gemm<64,128,0,5,1,2,0,1,0,4,64,96,64,96,224,35><<<dim3(192, 1), 256, 0, stream>>>(
        hx2, (const u16*)zf, h1f, wq2, gq2_b, zpg, h2bf, nullptr, outH, 128, 128, 0, 0);

    // ---- flow head ----
    k_gemm<64,128,0,1,1,0,0,1,2,0,64,96,64,96,128,4><<<dim3(192, 2), 256, 0, stream>>>(
        h2bf, nullptr, nullptr, wfh1, fh_b1, zpg, s1b, nullptr, nullptr, 256, 256, 0, 0);
    k_gemm<64,64,0,1,1,0,0,1,2,1,64,96,64,96,256,8><<<dim3(192, 1), 256, 0, stream>>>(
        s1b, nullptr, nullptr, wfh2, fh_b2, zpg, nullptr, nullptr, s2, 49, 64, 0, 0);
    k_soft<<<nb(12288, 256), 256, 0, stream>>>(s2, flow, outFlow);
}